// Round 6
// baseline (161.292 us; speedup 1.0000x reference)
//
#include <hip/hip_runtime.h>

typedef __attribute__((ext_vector_type(8))) short short8;
typedef __attribute__((ext_vector_type(4))) float float4v;
typedef __attribute__((ext_vector_type(4))) unsigned short us4;

namespace {
constexpr int NG   = 16;
constexpr int LSEQ = 4096;
constexpr int CIN  = 1024;
constexpr int IPG  = 64;
constexpr int OPG  = 64;
constexpr int KT   = 5;
constexpr int KSTEPS = 10;                // 320 K / 32
constexpr size_t WFRAG_SHORTS = (size_t)NG * 4 * KSTEPS * 512;  // 327,680
constexpr size_t WFRAG_BYTES  = WFRAG_SHORTS * 2;               // 655,360
}

__device__ __forceinline__ unsigned short f2bf(float f) {
  unsigned int u = __builtin_bit_cast(unsigned int, f);
  u += 0x7fffu + ((u >> 16) & 1u);   // RNE (inputs finite)
  return (unsigned short)(u >> 16);
}

// pack 8 fp32 -> short8 bf16 — scalar f2bf path (bit-identical to R3/R4 staging)
__device__ __forceinline__ short8 cvt8(float4v v0, float4v v1) {
  short8 r;
  r[0] = (short)f2bf(v0[0]);
  r[1] = (short)f2bf(v0[1]);
  r[2] = (short)f2bf(v0[2]);
  r[3] = (short)f2bf(v0[3]);
  r[4] = (short)f2bf(v1[0]);
  r[5] = (short)f2bf(v1[1]);
  r[6] = (short)f2bf(v1[2]);
  r[7] = (short)f2bf(v1[3]);
  return r;
}

// ---------------- prep: W (16,64,64,5) fp32 -> d_ws bf16 in B-frag layout ----
__global__ __launch_bounds__(256) void wprep(const float* __restrict__ gwt,
                                             unsigned short* __restrict__ wfrag) {
  const int u = blockIdx.x * 256 + threadIdx.x;           // 40960 threads
  const int E    = u * 8;
  const int tile = E >> 9;
  const int w9   = E & 511;
  const int n    = w9 >> 5;
  const int quad = (w9 & 31) >> 3;
  const int ks   = tile % KSTEPS;
  const int tt   = tile / KSTEPS;
  const int t    = tt & 3;
  const int g    = tt >> 2;
  const int tap  = ks >> 1;
  const int h    = ks & 1;
  const int o    = t * 16 + n;
  const float* src = gwt + (((size_t)(g * 64 + o) * 64) + h * 32 + quad * 8) * KT + tap;
  short8 v;
  #pragma unroll
  for (int j = 0; j < 8; ++j)
    v[j] = (short)f2bf(src[j * KT]);
  *(short8*)(wfrag + E) = v;
}

// ---------------- main: barrier-free, LDS-free streaming waves --------------
// Each wave: 32 rows x 64 out-cols of one (g, b). Block = 4 consecutive strips.
__global__ __launch_bounds__(256, 4) void mconv_stream(
    const float* __restrict__ gin,            // (4,4096,1024) fp32
    const int* __restrict__ gpos,             // (4,4096)
    const unsigned short* __restrict__ wfrag, // bf16 B-frags
    float* __restrict__ gout) {               // (4,4096,16,64) fp32
  const int tid  = threadIdx.x;
  const int wv   = tid >> 6;
  const int lane = tid & 63;
  const int quad = lane >> 4;
  const int l16  = lane & 15;

  const int g  = blockIdx.y;
  const int b  = blockIdx.z;
  const int strip0 = blockIdx.x * 128 + wv * 32;   // this wave's 32 rows
  const int bL = b * LSEQ;

  // ---- per-lane mask bits for the 2 m-tiles (5 bits each)
  int mb[2];
  #pragma unroll
  for (int mt = 0; mt < 2; ++mt) {
    const int l  = strip0 + mt * 16 + l16;
    const int pc = gpos[bL + l];
    unsigned int bits = 0;
    #pragma unroll
    for (int tap = 0; tap < KT; ++tap) {
      const int lsrc = l + tap - 2;
      const int lc   = min(max(lsrc, 0), LSEQ - 1);
      const int ok   = (lsrc == lc) & (gpos[bL + lc] == pc + (tap - 2));
      bits |= (unsigned int)ok << tap;
    }
    mb[mt] = (int)bits;
  }

  // ---- B-frag base: tile (g, nt, ks) at wfrag + ((g*4+nt)*KSTEPS + ks)*512
  const unsigned short* wbase = wfrag + (size_t)(g * 4) * KSTEPS * 512
                                      + l16 * 32 + quad * 8;

  const short8 zero8 = {0, 0, 0, 0, 0, 0, 0, 0};
  const float4v zf = {0.f, 0.f, 0.f, 0.f};
  float4v acc[2][4];   // [mt][nt]
  #pragma unroll
  for (int mt = 0; mt < 2; ++mt)
    #pragma unroll
    for (int nt = 0; nt < 4; ++nt)
      acc[mt][nt] = zf;

  const float* ginb = gin + (size_t)bL * CIN + g * IPG + quad * 8;

  #pragma unroll
  for (int tap = 0; tap < KT; ++tap) {
    // A-frags for both halves h=0,1; both m-tiles. Direct global load + cvt.
    short8 afr[2][2];  // [mt][h]
    #pragma unroll
    for (int mt = 0; mt < 2; ++mt) {
      const int lsrc = strip0 + mt * 16 + l16 + tap - 2;
      const int lc   = min(max(lsrc, 0), LSEQ - 1);
      const float* rp = ginb + (size_t)lc * CIN;
      const bool ok = (mb[mt] >> tap) & 1;
      #pragma unroll
      for (int h = 0; h < 2; ++h) {
        float4v v0 = *(const float4v*)(rp + h * 32);
        float4v v1 = *(const float4v*)(rp + h * 32 + 4);
        short8 a = cvt8(v0, v1);
        if (!ok) a = zero8;
        afr[mt][h] = a;
      }
    }
    #pragma unroll
    for (int h = 0; h < 2; ++h) {
      const int ks = tap * 2 + h;
      #pragma unroll
      for (int nt = 0; nt < 4; ++nt) {
        const short8 bfr = *(const short8*)(wbase + (size_t)(nt * KSTEPS + ks) * 512);
        acc[0][nt] = __builtin_amdgcn_mfma_f32_16x16x32_bf16(afr[0][h], bfr, acc[0][nt], 0, 0, 0);
        acc[1][nt] = __builtin_amdgcn_mfma_f32_16x16x32_bf16(afr[1][h], bfr, acc[1][nt], 0, 0, 0);
      }
    }
  }

  // ---- epilogue: C/D layout col=l16 (within n-tile), row=quad*4+reg
  #pragma unroll
  for (int mt = 0; mt < 2; ++mt) {
    const int lrow = strip0 + mt * 16 + quad * 4;
    #pragma unroll
    for (int reg = 0; reg < 4; ++reg) {
      float* orow = gout + (size_t)(bL + lrow + reg) * CIN + g * OPG;
      #pragma unroll
      for (int nt = 0; nt < 4; ++nt)
        orow[nt * 16 + l16] = acc[mt][nt][reg];
    }
  }
}

// ---------------- fallback (known-good R3 kernel, used if ws too small) -----
namespace fb {
constexpr int ROWS_PER_CHUNK = 128;
constexpr int CHUNKS = 4;
constexpr int ROWS_PER_BLOCK = 512;
constexpr int SW_STRIDE  = 328;
constexpr int FSIN_STRIDE = 72;
constexpr int FSIN_ROWS   = 132;
}

__global__ __launch_bounds__(256, 2) void mconv_f32_mfma(
    const float* __restrict__ gin, const int* __restrict__ gpos,
    const float* __restrict__ gwt, float* __restrict__ gout) {
  using namespace fb;
  __shared__ __align__(16) unsigned short sW[OPG * SW_STRIDE];
  __shared__ __align__(16) unsigned short sIn[FSIN_ROWS * FSIN_STRIDE];
  __shared__ unsigned char sMask[ROWS_PER_CHUNK * KT];

  const int tid  = threadIdx.x;
  const int wave = tid >> 6;
  const int lane = tid & 63;
  const int quad = lane >> 4;
  const int l16  = lane & 15;
  const int g  = blockIdx.y;
  const int b  = blockIdx.z;
  const int tile0 = blockIdx.x * ROWS_PER_BLOCK;
  const int bL = b * LSEQ;

  {
    const float* wg = gwt + (size_t)g * (OPG * IPG * KT);
    for (int u = tid; u < (OPG * IPG * KT) / 4; u += 256) {
      const int base = u * 4;
      float4v v = *(const float4v*)(wg + base);
      int o = base / (IPG * KT);
      int r = base - o * (IPG * KT);
      int i = r / KT;
      int k = r - i * KT;
      int addr = o * SW_STRIDE + k * IPG + i;
      #pragma unroll
      for (int t = 0; t < 4; ++t) {
        sW[addr] = f2bf(v[t]);
        ++k; addr += IPG;
        if (k == KT) { k = 0; ++i; addr -= KT * IPG - 1; }
      }
    }
  }
  const short8 zero8 = {0,0,0,0,0,0,0,0};
  const float4v zf = {0.f,0.f,0.f,0.f};
  for (int ch = 0; ch < CHUNKS; ++ch) {
    const int l0 = tile0 + ch * ROWS_PER_CHUNK;
    __syncthreads();
    for (int t = tid; t < ROWS_PER_CHUNK * KT; t += 256) {
      const int lr = t / KT, tap = t - lr * KT, l = l0 + lr, lsrc = l + tap - 2;
      int ok = 0;
      if (lsrc >= 0 && lsrc < LSEQ) ok = (gpos[bL + lsrc] == gpos[bL + l] + (tap - 2));
      sMask[t] = (unsigned char)ok;
    }
    for (int u = tid; u < FSIN_ROWS * 16; u += 256) {
      const int r = u >> 4, c4 = u & 15, l = l0 - 2 + r;
      us4 w = {0,0,0,0};
      if (l >= 0 && l < LSEQ) {
        float4v v = *(const float4v*)(gin + (size_t)(bL + l) * CIN + g * IPG + c4 * 4);
        w[0]=f2bf(v[0]); w[1]=f2bf(v[1]); w[2]=f2bf(v[2]); w[3]=f2bf(v[3]);
      }
      *(us4*)(&sIn[r * FSIN_STRIDE + c4 * 4]) = w;
    }
    __syncthreads();
    float4v acc[2][4];
    #pragma unroll
    for (int mm = 0; mm < 2; ++mm)
      #pragma unroll
      for (int nt = 0; nt < 4; ++nt) acc[mm][nt] = zf;
    const int m0 = wave * 32 + l16, m1 = m0 + 16;
    #pragma unroll
    for (int tap = 0; tap < KT; ++tap) {
      const bool msk0 = sMask[m0 * KT + tap] != 0;
      const bool msk1 = sMask[m1 * KT + tap] != 0;
      #pragma unroll
      for (int h = 0; h < 2; ++h) {
        const int kk = tap * IPG + h * 32 + quad * 8;
        const short8 b0 = *(const short8*)(&sW[(0*16 + l16) * SW_STRIDE + kk]);
        const short8 b1 = *(const short8*)(&sW[(1*16 + l16) * SW_STRIDE + kk]);
        const short8 b2 = *(const short8*)(&sW[(2*16 + l16) * SW_STRIDE + kk]);
        const short8 b3 = *(const short8*)(&sW[(3*16 + l16) * SW_STRIDE + kk]);
        const int ci = h * 32 + quad * 8;
        short8 a0 = *(const short8*)(&sIn[(m0 + tap) * FSIN_STRIDE + ci]);
        short8 a1 = *(const short8*)(&sIn[(m1 + tap) * FSIN_STRIDE + ci]);
        if (!msk0) a0 = zero8;
        if (!msk1) a1 = zero8;
        acc[0][0] = __builtin_amdgcn_mfma_f32_16x16x32_bf16(a0,b0,acc[0][0],0,0,0);
        acc[0][1] = __builtin_amdgcn_mfma_f32_16x16x32_bf16(a0,b1,acc[0][1],0,0,0);
        acc[0][2] = __builtin_amdgcn_mfma_f32_16x16x32_bf16(a0,b2,acc[0][2],0,0,0);
        acc[0][3] = __builtin_amdgcn_mfma_f32_16x16x32_bf16(a0,b3,acc[0][3],0,0,0);
        acc[1][0] = __builtin_amdgcn_mfma_f32_16x16x32_bf16(a1,b0,acc[1][0],0,0,0);
        acc[1][1] = __builtin_amdgcn_mfma_f32_16x16x32_bf16(a1,b1,acc[1][1],0,0,0);
        acc[1][2] = __builtin_amdgcn_mfma_f32_16x16x32_bf16(a1,b2,acc[1][2],0,0,0);
        acc[1][3] = __builtin_amdgcn_mfma_f32_16x16x32_bf16(a1,b3,acc[1][3],0,0,0);
      }
    }
    #pragma unroll
    for (int mm = 0; mm < 2; ++mm) {
      const int lrow = l0 + wave * 32 + mm * 16 + quad * 4;
      #pragma unroll
      for (int reg = 0; reg < 4; ++reg) {
        float* orow = gout + ((size_t)(bL + lrow + reg) * NG + g) * OPG;
        #pragma unroll
        for (int nt = 0; nt < 4; ++nt)
          orow[nt * 16 + l16] = acc[mm][nt][reg];
      }
    }
  }
}

extern "C" void kernel_launch(void* const* d_in, const int* in_sizes, int n_in,
                              void* d_out, int out_size, void* d_ws, size_t ws_size,
                              hipStream_t stream) {
  (void)in_sizes; (void)n_in; (void)out_size;
  const float* gin  = (const float*)d_in[0];
  const int*   gpos = (const int*)d_in[1];
  const float* gwt  = (const float*)d_in[2];
  float*       gout = (float*)d_out;

  if (ws_size >= WFRAG_BYTES) {
    unsigned short* wfrag = (unsigned short*)d_ws;
    hipLaunchKernelGGL(wprep, dim3(160), dim3(256), 0, stream, gwt, wfrag);
    dim3 grid(LSEQ / 128, NG, 4);   // 32 x 16 x 4 = 2048 blocks, 4 waves each
    hipLaunchKernelGGL(mconv_stream, grid, dim3(256), 0, stream,
                       gin, gpos, wfrag, gout);
  } else {
    dim3 grid(LSEQ / fb::ROWS_PER_BLOCK, NG, 4);
    hipLaunchKernelGGL(mconv_f32_mfma, grid, dim3(256), 0, stream,
                       gin, gpos, gwt, gout);
  }
}

// Round 7
// 140.022 us; speedup vs baseline: 1.1519x; 1.1519x over previous
//
#include <hip/hip_runtime.h>

typedef __attribute__((ext_vector_type(8))) short short8;
typedef __attribute__((ext_vector_type(4))) float float4v;
typedef __attribute__((ext_vector_type(4))) unsigned short us4;

namespace {
constexpr int NG   = 16;
constexpr int LSEQ = 4096;
constexpr int CIN  = 1024;
constexpr int IPG  = 64;
constexpr int OPG  = 64;
constexpr int KT   = 5;
constexpr int KSTEPS = 10;                 // 320 K / 32
constexpr int SSTR = 72;                   // sIn row stride (shorts); dword-stride 36 ≡ 4 mod 32
constexpr int SEGR = 36;                   // rows per wave segment (32 + 4 halo)
constexpr int SEG  = SEGR * SSTR;          // 2592 shorts = 5184 B per wave
constexpr size_t WFRAG_SHORTS = (size_t)NG * 4 * KSTEPS * 512;  // 327,680
constexpr size_t WFRAG_BYTES  = WFRAG_SHORTS * 2;               // 655,360
}

__device__ __forceinline__ unsigned short f2bf(float f) {
  unsigned int u = __builtin_bit_cast(unsigned int, f);
  u += 0x7fffu + ((u >> 16) & 1u);   // RNE (inputs finite)
  return (unsigned short)(u >> 16);
}

// ---------------- prep: W (16,64,64,5) fp32 -> d_ws bf16 in B-frag layout ----
__global__ __launch_bounds__(256) void wprep(const float* __restrict__ gwt,
                                             unsigned short* __restrict__ wfrag) {
  const int u = blockIdx.x * 256 + threadIdx.x;           // 40960 threads
  const int E    = u * 8;
  const int tile = E >> 9;
  const int w9   = E & 511;
  const int n    = w9 >> 5;
  const int quad = (w9 & 31) >> 3;
  const int ks   = tile % KSTEPS;
  const int tt   = tile / KSTEPS;
  const int t    = tt & 3;
  const int g    = tt >> 2;
  const int tap  = ks >> 1;
  const int h    = ks & 1;
  const int o    = t * 16 + n;
  const float* src = gwt + (((size_t)(g * 64 + o) * 64) + h * 32 + quad * 8) * KT + tap;
  short8 v;
  #pragma unroll
  for (int j = 0; j < 8; ++j)
    v[j] = (short)f2bf(src[j * KT]);
  *(short8*)(wfrag + E) = v;
}

// ------- main: barrier-free; wave-private LDS staging (read-once, 5x reuse) --
__global__ __launch_bounds__(256, 6) void mconv_wls(
    const float* __restrict__ gin,            // (4,4096,1024) fp32
    const int* __restrict__ gpos,             // (4,4096)
    const unsigned short* __restrict__ wfrag, // bf16 B-frags
    float* __restrict__ gout) {               // (4,4096,16,64) fp32
  __shared__ __align__(16) unsigned short sIn[4 * SEG];   // 20736 B, 4 wave segments

  const int tid  = threadIdx.x;
  const int wv   = tid >> 6;
  const int lane = tid & 63;
  const int quad = lane >> 4;
  const int l16  = lane & 15;

  const int g  = blockIdx.y;
  const int b  = blockIdx.z;
  const int strip0 = blockIdx.x * 128 + wv * 32;   // this wave's 32 rows
  const int bL = b * LSEQ;

  unsigned short* ws = sIn + wv * SEG;             // wave-private segment

  // ---- stage rows [strip0-2, strip0+34) into private LDS, fp32->bf16 once
  {
    const float* gi = gin + (size_t)bL * CIN + g * IPG;
    #pragma unroll
    for (int t = 0; t < 9; ++t) {                  // 9*64 = 576 = 36 rows * 16 f4
      const int idx = t * 64 + lane;
      const int r   = idx >> 4;
      const int c4  = idx & 15;
      const int l   = strip0 - 2 + r;
      const int lc  = min(max(l, 0), LSEQ - 1);
      float4v v = *(const float4v*)(gi + (size_t)lc * CIN + c4 * 4);
      us4 w;
      w[0] = f2bf(v[0]); w[1] = f2bf(v[1]); w[2] = f2bf(v[2]); w[3] = f2bf(v[3]);
      if (l != lc) w = us4{0, 0, 0, 0};            // OOB rows -> zero
      *(us4*)(&ws[r * SSTR + c4 * 4]) = w;         // ds_write_b64
    }
  }

  // ---- per-lane mask bits for the 2 m-tiles (5 bits each)
  int mb[2];
  #pragma unroll
  for (int mt = 0; mt < 2; ++mt) {
    const int l  = strip0 + mt * 16 + l16;
    const int pc = gpos[bL + l];
    unsigned int bits = 0;
    #pragma unroll
    for (int tap = 0; tap < KT; ++tap) {
      const int lsrc = l + tap - 2;
      const int lc   = min(max(lsrc, 0), LSEQ - 1);
      const int ok   = (lsrc == lc) & (gpos[bL + lc] == pc + (tap - 2));
      bits |= (unsigned int)ok << tap;
    }
    mb[mt] = (int)bits;
  }

  // ---- B-frag base: tile (g, nt, ks) at wfrag + ((g*4+nt)*KSTEPS + ks)*512
  const unsigned short* wbase = wfrag + (size_t)(g * 4) * KSTEPS * 512
                                      + l16 * 32 + quad * 8;

  const short8 zero8 = {0, 0, 0, 0, 0, 0, 0, 0};
  const float4v zf = {0.f, 0.f, 0.f, 0.f};
  float4v acc[2][4];   // [mt][nt]
  #pragma unroll
  for (int mt = 0; mt < 2; ++mt)
    #pragma unroll
    for (int nt = 0; nt < 4; ++nt)
      acc[mt][nt] = zf;

  // (compiler inserts lgkmcnt wait between same-wave ds_write and ds_read;
  //  LDS segment is wave-private so no __syncthreads is needed)
  #pragma unroll
  for (int tap = 0; tap < KT; ++tap) {
    short8 afr[2][2];  // [mt][h]
    #pragma unroll
    for (int mt = 0; mt < 2; ++mt) {
      const int row = mt * 16 + l16 + tap;         // 0..35 in segment
      const bool ok = (mb[mt] >> tap) & 1;
      #pragma unroll
      for (int h = 0; h < 2; ++h) {
        short8 a = *(const short8*)(&ws[row * SSTR + h * 32 + quad * 8]); // ds_read_b128
        if (!ok) a = zero8;
        afr[mt][h] = a;
      }
    }
    #pragma unroll
    for (int h = 0; h < 2; ++h) {
      const int ks = tap * 2 + h;
      #pragma unroll
      for (int nt = 0; nt < 4; ++nt) {
        const short8 bfr = *(const short8*)(wbase + (size_t)(nt * KSTEPS + ks) * 512);
        acc[0][nt] = __builtin_amdgcn_mfma_f32_16x16x32_bf16(afr[0][h], bfr, acc[0][nt], 0, 0, 0);
        acc[1][nt] = __builtin_amdgcn_mfma_f32_16x16x32_bf16(afr[1][h], bfr, acc[1][nt], 0, 0, 0);
      }
    }
  }

  // ---- epilogue: C/D layout col=l16 (within n-tile), row=quad*4+reg
  #pragma unroll
  for (int mt = 0; mt < 2; ++mt) {
    const int lrow = strip0 + mt * 16 + quad * 4;
    #pragma unroll
    for (int reg = 0; reg < 4; ++reg) {
      float* orow = gout + (size_t)(bL + lrow + reg) * CIN + g * OPG;
      #pragma unroll
      for (int nt = 0; nt < 4; ++nt)
        orow[nt * 16 + l16] = acc[mt][nt][reg];
    }
  }
}

// ---------------- fallback (known-good R3 kernel, used if ws too small) -----
namespace fb {
constexpr int ROWS_PER_CHUNK = 128;
constexpr int CHUNKS = 4;
constexpr int ROWS_PER_BLOCK = 512;
constexpr int SW_STRIDE  = 328;
constexpr int FSIN_STRIDE = 72;
constexpr int FSIN_ROWS   = 132;
}

__global__ __launch_bounds__(256, 2) void mconv_f32_mfma(
    const float* __restrict__ gin, const int* __restrict__ gpos,
    const float* __restrict__ gwt, float* __restrict__ gout) {
  using namespace fb;
  __shared__ __align__(16) unsigned short sW[OPG * SW_STRIDE];
  __shared__ __align__(16) unsigned short sIn[FSIN_ROWS * FSIN_STRIDE];
  __shared__ unsigned char sMask[ROWS_PER_CHUNK * KT];

  const int tid  = threadIdx.x;
  const int wave = tid >> 6;
  const int lane = tid & 63;
  const int quad = lane >> 4;
  const int l16  = lane & 15;
  const int g  = blockIdx.y;
  const int b  = blockIdx.z;
  const int tile0 = blockIdx.x * ROWS_PER_BLOCK;
  const int bL = b * LSEQ;

  {
    const float* wg = gwt + (size_t)g * (OPG * IPG * KT);
    for (int u = tid; u < (OPG * IPG * KT) / 4; u += 256) {
      const int base = u * 4;
      float4v v = *(const float4v*)(wg + base);
      int o = base / (IPG * KT);
      int r = base - o * (IPG * KT);
      int i = r / KT;
      int k = r - i * KT;
      int addr = o * SW_STRIDE + k * IPG + i;
      #pragma unroll
      for (int t = 0; t < 4; ++t) {
        sW[addr] = f2bf(v[t]);
        ++k; addr += IPG;
        if (k == KT) { k = 0; ++i; addr -= KT * IPG - 1; }
      }
    }
  }
  const short8 zero8 = {0,0,0,0,0,0,0,0};
  const float4v zf = {0.f,0.f,0.f,0.f};
  for (int ch = 0; ch < CHUNKS; ++ch) {
    const int l0 = tile0 + ch * ROWS_PER_CHUNK;
    __syncthreads();
    for (int t = tid; t < ROWS_PER_CHUNK * KT; t += 256) {
      const int lr = t / KT, tap = t - lr * KT, l = l0 + lr, lsrc = l + tap - 2;
      int ok = 0;
      if (lsrc >= 0 && lsrc < LSEQ) ok = (gpos[bL + lsrc] == gpos[bL + l] + (tap - 2));
      sMask[t] = (unsigned char)ok;
    }
    for (int u = tid; u < FSIN_ROWS * 16; u += 256) {
      const int r = u >> 4, c4 = u & 15, l = l0 - 2 + r;
      us4 w = {0,0,0,0};
      if (l >= 0 && l < LSEQ) {
        float4v v = *(const float4v*)(gin + (size_t)(bL + l) * CIN + g * IPG + c4 * 4);
        w[0]=f2bf(v[0]); w[1]=f2bf(v[1]); w[2]=f2bf(v[2]); w[3]=f2bf(v[3]);
      }
      *(us4*)(&sIn[r * FSIN_STRIDE + c4 * 4]) = w;
    }
    __syncthreads();
    float4v acc[2][4];
    #pragma unroll
    for (int mm = 0; mm < 2; ++mm)
      #pragma unroll
      for (int nt = 0; nt < 4; ++nt) acc[mm][nt] = zf;
    const int m0 = wave * 32 + l16, m1 = m0 + 16;
    #pragma unroll
    for (int tap = 0; tap < KT; ++tap) {
      const bool msk0 = sMask[m0 * KT + tap] != 0;
      const bool msk1 = sMask[m1 * KT + tap] != 0;
      #pragma unroll
      for (int h = 0; h < 2; ++h) {
        const int kk = tap * IPG + h * 32 + quad * 8;
        const short8 b0 = *(const short8*)(&sW[(0*16 + l16) * SW_STRIDE + kk]);
        const short8 b1 = *(const short8*)(&sW[(1*16 + l16) * SW_STRIDE + kk]);
        const short8 b2 = *(const short8*)(&sW[(2*16 + l16) * SW_STRIDE + kk]);
        const short8 b3 = *(const short8*)(&sW[(3*16 + l16) * SW_STRIDE + kk]);
        const int ci = h * 32 + quad * 8;
        short8 a0 = *(const short8*)(&sIn[(m0 + tap) * FSIN_STRIDE + ci]);
        short8 a1 = *(const short8*)(&sIn[(m1 + tap) * FSIN_STRIDE + ci]);
        if (!msk0) a0 = zero8;
        if (!msk1) a1 = zero8;
        acc[0][0] = __builtin_amdgcn_mfma_f32_16x16x32_bf16(a0,b0,acc[0][0],0,0,0);
        acc[0][1] = __builtin_amdgcn_mfma_f32_16x16x32_bf16(a0,b1,acc[0][1],0,0,0);
        acc[0][2] = __builtin_amdgcn_mfma_f32_16x16x32_bf16(a0,b2,acc[0][2],0,0,0);
        acc[0][3] = __builtin_amdgcn_mfma_f32_16x16x32_bf16(a0,b3,acc[0][3],0,0,0);
        acc[1][0] = __builtin_amdgcn_mfma_f32_16x16x32_bf16(a1,b0,acc[1][0],0,0,0);
        acc[1][1] = __builtin_amdgcn_mfma_f32_16x16x32_bf16(a1,b1,acc[1][1],0,0,0);
        acc[1][2] = __builtin_amdgcn_mfma_f32_16x16x32_bf16(a1,b2,acc[1][2],0,0,0);
        acc[1][3] = __builtin_amdgcn_mfma_f32_16x16x32_bf16(a1,b3,acc[1][3],0,0,0);
      }
    }
    #pragma unroll
    for (int mm = 0; mm < 2; ++mm) {
      const int lrow = l0 + wave * 32 + mm * 16 + quad * 4;
      #pragma unroll
      for (int reg = 0; reg < 4; ++reg) {
        float* orow = gout + ((size_t)(bL + lrow + reg) * NG + g) * OPG;
        #pragma unroll
        for (int nt = 0; nt < 4; ++nt)
          orow[nt * 16 + l16] = acc[mm][nt][reg];
      }
    }
  }
}

extern "C" void kernel_launch(void* const* d_in, const int* in_sizes, int n_in,
                              void* d_out, int out_size, void* d_ws, size_t ws_size,
                              hipStream_t stream) {
  (void)in_sizes; (void)n_in; (void)out_size;
  const float* gin  = (const float*)d_in[0];
  const int*   gpos = (const int*)d_in[1];
  const float* gwt  = (const float*)d_in[2];
  float*       gout = (float*)d_out;

  if (ws_size >= WFRAG_BYTES) {
    unsigned short* wfrag = (unsigned short*)d_ws;
    hipLaunchKernelGGL(wprep, dim3(160), dim3(256), 0, stream, gwt, wfrag);
    dim3 grid(LSEQ / 128, NG, 4);   // 32 x 16 x 4 = 2048 blocks, 4 indep waves
    hipLaunchKernelGGL(mconv_wls, grid, dim3(256), 0, stream,
                       gin, gpos, wfrag, gout);
  } else {
    dim3 grid(LSEQ / fb::ROWS_PER_BLOCK, NG, 4);
    hipLaunchKernelGGL(mconv_f32_mfma, grid, dim3(256), 0, stream,
                       gin, gpos, gwt, gout);
  }
}